// Round 20
// baseline (284.985 us; speedup 1.0000x reference)
//
#include <hip/hip_runtime.h>
#include <math.h>

typedef _Float16 half8 __attribute__((ext_vector_type(8)));
typedef float f32x4 __attribute__((ext_vector_type(4)));

__device__ inline uint splitpack(float v) {
    _Float16 h = (_Float16)v;
    float r = v - (float)h;
    _Float16 l = (_Float16)r;
    return (uint)__builtin_bit_cast(unsigned short, h) |
           ((uint)__builtin_bit_cast(unsigned short, l) << 16);
}
__device__ inline _Float16 lo16h(uint u) { return __builtin_bit_cast(_Float16, (unsigned short)(u & 0xffffu)); }
__device__ inline _Float16 hi16h(uint u) { return __builtin_bit_cast(_Float16, (unsigned short)(u >> 16)); }
__device__ inline uint packhh(_Float16 a, _Float16 b) {
    return (uint)__builtin_bit_cast(unsigned short, a) |
           ((uint)__builtin_bit_cast(unsigned short, b) << 16);
}
__device__ inline float dpp_max8(float v) {
    int x = __builtin_amdgcn_mov_dpp(__builtin_bit_cast(int, v), 0x128, 0xf, 0xf, true);
    return fmaxf(v, __builtin_bit_cast(float, x));
}

// ---------------- conv1: 512 threads (8 waves) for occupancy; compact p1 [N][6][196] ----------------
// Same 2 imgs/block, same LDS (27.1 KB), same per-wave tile assignment (t === wv mod 8),
// same 2-tile pipelining (t0, t0+8). 4 blocks/CU x 8 waves = 32 waves/CU cap (was ~13 measured).
__global__ __launch_bounds__(512) void k_conv1(const float* __restrict__ x,
                                               const float* __restrict__ w,
                                               const float* __restrict__ b,
                                               uint* __restrict__ p1) {
    __shared__ uint simg[6720];
    const int tid  = threadIdx.x;
    const int lane = tid & 63;
    const int wv   = tid >> 6;          // 0..7
    const int n0   = blockIdx.x * 2;

    const int colb = lane & 15;
    const int c  = colb & 7, dx = colb >> 3;
    const int g  = lane >> 4;
    const int qr = g;

    half8 bh[3], bl[3];
    #pragma unroll
    for (int ks = 0; ks < 3; ++ks)
        #pragma unroll
        for (int jj = 0; jj < 8; ++jj) {
            int pi = jj >> 1, e = jj & 1;
            int rho = g * 4 + pi;
            float val = 0.f;
            if (rho < 15 && c < 6) {
                int ci = rho / 5, ky = rho % 5;
                int kx = ks * 2 + e - dx;
                if (kx >= 0 && kx < 5) val = w[c * 75 + ci * 25 + ky * 5 + kx];
            }
            _Float16 hh = (_Float16)val;
            bh[ks][jj] = hh;
            bl[ks][jj] = (_Float16)(val - (float)hh);
        }
    const float bias = (c < 6) ? b[c] : 0.f;

    for (int i = tid; i < 1536; i += 512) {
        int im = i / 768;
        int rem = i - im * 768;
        int plane = rem >> 8, rr = (rem & 255) >> 3, f = rem & 7;
        float4 v = *(const float4*)(x + ((size_t)(n0 + im) * 3 + plane) * 1024 + rr * 32 + f * 4);
        _Float16 h0 = (_Float16)v.x, h1 = (_Float16)v.y, h2 = (_Float16)v.z, h3 = (_Float16)v.w;
        _Float16 l0 = (_Float16)(v.x - (float)h0), l1 = (_Float16)(v.y - (float)h1);
        _Float16 l2 = (_Float16)(v.z - (float)h2), l3 = (_Float16)(v.w - (float)h3);
        int base = im * 3360 + plane * 1120 + rr * 35 + f * 2;
        simg[base]      = packhh(h0, h1);
        simg[base + 1]  = packhh(h2, h3);
        simg[base + 16] = packhh(l0, l1);
        simg[base + 17] = packhh(l2, l3);
    }
    __syncthreads();

    int poff[4];
    #pragma unroll
    for (int pi = 0; pi < 4; ++pi) {
        int rho = g * 4 + pi;
        if (rho > 14) rho = 14;
        poff[pi] = (rho / 5) * 1120 + (rho % 5) * 35;
    }

    for (int t0 = wv; t0 < 50; t0 += 16) {
        const int t1 = (t0 + 8 < 50) ? (t0 + 8) : t0;
        const int im0 = (t0 >= 25) ? 1 : 0, tl0 = t0 - im0 * 25;
        const int im1 = (t1 >= 25) ? 1 : 0, tl1 = t1 - im1 * 25;
        int r0c = tl0 * 16 + colb; if (r0c > 391) r0c = 391;
        int r1c = tl1 * 16 + colb; if (r1c > 391) r1c = 391;
        int qx0 = (r0c * 586) >> 14, yy0 = r0c - qx0 * 28;
        int qx1 = (r1c * 586) >> 14, yy1 = r1c - qx1 * 28;
        const uint* base0 = simg + im0 * 3360 + yy0 * 35 + qx0;
        const uint* base1 = simg + im1 * 3360 + yy1 * 35 + qx1;

        f32x4 A0[2] = {{0.f,0.f,0.f,0.f},{0.f,0.f,0.f,0.f}};
        f32x4 A1[2] = {{0.f,0.f,0.f,0.f},{0.f,0.f,0.f,0.f}};
        int c0 = 0, c1 = 0;
        #pragma unroll
        for (int ks = 0; ks < 3; ++ks) {
            uint h0[4], l0[4], h1[4], l1[4];
            #pragma unroll
            for (int pi = 0; pi < 4; ++pi) {
                const uint* a0p = base0 + poff[pi];
                const uint* a1p = base1 + poff[pi];
                h0[pi] = a0p[ks];  l0[pi] = a0p[16 + ks];
                h1[pi] = a1p[ks];  l1[pi] = a1p[16 + ks];
            }
            uint4 hv0; hv0.x = h0[0]; hv0.y = h0[1]; hv0.z = h0[2]; hv0.w = h0[3];
            uint4 lv0; lv0.x = l0[0]; lv0.y = l0[1]; lv0.z = l0[2]; lv0.w = l0[3];
            uint4 hv1; hv1.x = h1[0]; hv1.y = h1[1]; hv1.z = h1[2]; hv1.w = h1[3];
            uint4 lv1; lv1.x = l1[0]; lv1.y = l1[1]; lv1.z = l1[2]; lv1.w = l1[3];
            half8 ah0 = __builtin_bit_cast(half8, hv0);
            half8 al0 = __builtin_bit_cast(half8, lv0);
            half8 ah1 = __builtin_bit_cast(half8, hv1);
            half8 al1 = __builtin_bit_cast(half8, lv1);
            A0[c0 & 1] = __builtin_amdgcn_mfma_f32_16x16x32_f16(ah0, bh[ks], A0[c0 & 1], 0, 0, 0); ++c0;
            A1[c1 & 1] = __builtin_amdgcn_mfma_f32_16x16x32_f16(ah1, bh[ks], A1[c1 & 1], 0, 0, 0); ++c1;
            A0[c0 & 1] = __builtin_amdgcn_mfma_f32_16x16x32_f16(ah0, bl[ks], A0[c0 & 1], 0, 0, 0); ++c0;
            A1[c1 & 1] = __builtin_amdgcn_mfma_f32_16x16x32_f16(ah1, bl[ks], A1[c1 & 1], 0, 0, 0); ++c1;
            A0[c0 & 1] = __builtin_amdgcn_mfma_f32_16x16x32_f16(al0, bh[ks], A0[c0 & 1], 0, 0, 0); ++c0;
            A1[c1 & 1] = __builtin_amdgcn_mfma_f32_16x16x32_f16(al1, bh[ks], A1[c1 & 1], 0, 0, 0); ++c1;
        }
        {
            f32x4 acc;
            #pragma unroll
            for (int i = 0; i < 4; ++i) acc[i] = A0[0][i] + A0[1][i];
            float p01 = dpp_max8(fmaxf(acc[0], acc[1]));
            float p23 = dpp_max8(fmaxf(acc[2], acc[3]));
            if (dx == 0 && c < 6) {
                uint* outb = p1 + (size_t)(n0 + im0) * 1176 + c * 196;
                int r0 = tl0 * 16 + qr * 4;
                if (r0 + 1 < 392) {
                    int qxa = (r0 * 586) >> 14, ya = r0 - qxa * 28;
                    outb[(ya >> 1) * 14 + qxa] = splitpack(fmaxf(p01 + bias, 0.f));
                }
                int r2 = r0 + 2;
                if (r2 + 1 < 392) {
                    int qxb = (r2 * 586) >> 14, yb = r2 - qxb * 28;
                    outb[(yb >> 1) * 14 + qxb] = splitpack(fmaxf(p23 + bias, 0.f));
                }
            }
        }
        if (t1 != t0) {
            f32x4 acc;
            #pragma unroll
            for (int i = 0; i < 4; ++i) acc[i] = A1[0][i] + A1[1][i];
            float p01 = dpp_max8(fmaxf(acc[0], acc[1]));
            float p23 = dpp_max8(fmaxf(acc[2], acc[3]));
            if (dx == 0 && c < 6) {
                uint* outb = p1 + (size_t)(n0 + im1) * 1176 + c * 196;
                int r0 = tl1 * 16 + qr * 4;
                if (r0 + 1 < 392) {
                    int qxa = (r0 * 586) >> 14, ya = r0 - qxa * 28;
                    outb[(ya >> 1) * 14 + qxa] = splitpack(fmaxf(p01 + bias, 0.f));
                }
                int r2 = r0 + 2;
                if (r2 + 1 < 392) {
                    int qxb = (r2 * 586) >> 14, yb = r2 - qxb * 28;
                    outb[(yb >> 1) * 14 + qxb] = splitpack(fmaxf(p23 + bias, 0.f));
                }
            }
        }
    }
}

// ---------------- conv2 (round-19 verbatim): compact p1 -> p2 fp32 ----------------
__global__ __launch_bounds__(256) void k_conv2(const uint* __restrict__ p1,
                                               const float* __restrict__ w,
                                               const float* __restrict__ b,
                                               float* __restrict__ p2) {
    __shared__ __align__(16) uint simg[4 * 1176 + 8];
    const int tid  = threadIdx.x;
    const int lane = tid & 63;
    const int wv   = tid >> 6;
    const int n0   = blockIdx.x * 4;
    const int g  = lane >> 4;
    const int cc = lane & 15;
    const int qr = g;

    {
        const uint4* pg = (const uint4*)(p1 + (size_t)n0 * 1176);
        uint4* sg = (uint4*)simg;
        for (int i = tid; i < 1176; i += 256) sg[i] = pg[i];
        if (tid < 8) simg[4704 + tid] = 0u;
    }

    half8 bh[6], bl[6];
    #pragma unroll
    for (int ks = 0; ks < 6; ++ks)
        #pragma unroll
        for (int jj = 0; jj < 8; ++jj) {
            int pi = jj >> 1, e = jj & 1;
            int rho = (ks / 3) * 16 + g * 4 + pi;
            int kx = (ks % 3) * 2 + e;
            float val = 0.f;
            if (rho < 30 && kx < 5) {
                int ci = rho / 5, ky = rho % 5;
                val = w[cc * 150 + ci * 25 + ky * 5 + kx];
            }
            _Float16 hh = (_Float16)val;
            bh[ks][jj] = hh;
            bl[ks][jj] = (_Float16)(val - (float)hh);
        }
    const float bias = b[cc];
    __syncthreads();

    int poff2[8];
    #pragma unroll
    for (int sp = 0; sp < 8; ++sp) {
        int sel = sp >> 2, pi = sp & 3;
        int rho = sel * 16 + g * 4 + pi;
        if (rho > 29) rho = 29;
        poff2[sp] = (rho / 5) * 196 + (rho % 5) * 14;
    }

    const uint* img = simg + wv * 1176;
    const int qw  = (lane & 15) >> 2;
    const int dy  = (lane >> 1) & 1, dxx = lane & 1;
    float* outb = p2 + (size_t)(n0 + wv) * 400 + cc * 25;

    for (int t = 0; t < 7; ++t) {
        int qa = t * 4 + qw; if (qa > 24) qa = 24;
        int qy = qa / 5, qx = qa % 5;
        int base = (2 * qy + dy) * 14 + (2 * qx + dxx);
        f32x4 acc2[2] = {{0.f,0.f,0.f,0.f},{0.f,0.f,0.f,0.f}};
        int pp = 0;
        #pragma unroll
        for (int sel = 0; sel < 2; ++sel) {
            uint P[4][6];
            #pragma unroll
            for (int pi = 0; pi < 4; ++pi) {
                const uint* ap = img + base + poff2[sel * 4 + pi];
                #pragma unroll
                for (int k = 0; k < 6; ++k) P[pi][k] = ap[k];
            }
            #pragma unroll
            for (int ksr = 0; ksr < 3; ++ksr) {
                const int ks = sel * 3 + ksr;
                uint hu[4], lu[4];
                #pragma unroll
                for (int pi = 0; pi < 4; ++pi) {
                    uint d0 = P[pi][ksr * 2], d1 = P[pi][ksr * 2 + 1];
                    hu[pi] = __builtin_amdgcn_perm(d1, d0, 0x05040100u);
                    lu[pi] = __builtin_amdgcn_perm(d1, d0, 0x07060302u);
                }
                uint4 hv; hv.x = hu[0]; hv.y = hu[1]; hv.z = hu[2]; hv.w = hu[3];
                uint4 lv; lv.x = lu[0]; lv.y = lu[1]; lv.z = lu[2]; lv.w = lu[3];
                half8 ah = __builtin_bit_cast(half8, hv);
                half8 al = __builtin_bit_cast(half8, lv);
                acc2[pp & 1] = __builtin_amdgcn_mfma_f32_16x16x32_f16(ah, bh[ks], acc2[pp & 1], 0, 0, 0); ++pp;
                acc2[pp & 1] = __builtin_amdgcn_mfma_f32_16x16x32_f16(ah, bl[ks], acc2[pp & 1], 0, 0, 0); ++pp;
                acc2[pp & 1] = __builtin_amdgcn_mfma_f32_16x16x32_f16(al, bh[ks], acc2[pp & 1], 0, 0, 0); ++pp;
            }
        }
        int qc = t * 4 + qr;
        if (qc < 25) {
            float m = fmaxf(fmaxf(acc2[0][0] + acc2[1][0], acc2[0][1] + acc2[1][1]),
                            fmaxf(acc2[0][2] + acc2[1][2], acc2[0][3] + acc2[1][3]));
            outb[qc] = fmaxf(m + bias, 0.f);
        }
    }
}

// ---------------- compose (verbatim) ----------------
__global__ __launch_bounds__(256) void k_compose(const float* __restrict__ ew,
                                                 const float* __restrict__ eb,
                                                 const float* __restrict__ hw,
                                                 float* __restrict__ C,
                                                 float* __restrict__ hb2) {
    __shared__ float shw[840];
    __shared__ float seb[672];
    const int e = blockIdx.x, tid = threadIdx.x;
    for (int i = tid; i < 840; i += 256) shw[i] = hw[i];
    for (int i = tid; i < 672; i += 256) seb[i] = eb[i];
    __syncthreads();
    for (int i = tid; i < 840; i += 256) {
        int o = i / 84, d = i % 84;
        float s = 0.f;
        for (int j = 0; j < 84; ++j)
            s = fmaf(shw[o * 84 + j], ew[((size_t)e * 84 + j) * 84 + d], s);
        C[e * 840 + i] = s;
    }
    if (tid < 10) {
        float s = 0.f;
        for (int j = 0; j < 84; ++j) s = fmaf(shw[tid * 84 + j], seb[e * 84 + j], s);
        hb2[e * 10 + tid] = s;
    }
}

// ---------------- fused fc1(MFMA)+fc2+gate+MoE+head (round-19 verbatim) ----------------
__global__ __launch_bounds__(512) void k_fc1tail(const float* __restrict__ p2,
                                                 const float* __restrict__ f1w,
                                                 const float* __restrict__ f1b,
                                                 const float* __restrict__ f2w,
                                                 const float* __restrict__ f2b,
                                                 const float* __restrict__ gw,
                                                 const float* __restrict__ Cw,
                                                 const float* __restrict__ hb2,
                                                 const float* __restrict__ headb,
                                                 float* __restrict__ out) {
    __shared__ __align__(16) float region[23872];
    __shared__ float sh1[7744];
    __shared__ float sfb[84];
    __shared__ int   sei[128];
    const int tid = threadIdx.x;
    const int n0 = blockIdx.x * 64;

    {
        uint* hplu = (uint*)region;
        const int lane = tid & 63;
        const int wvv  = tid >> 6;
        const int cc = lane & 15, g = lane >> 4;
        const int outg = wvv * 16 + cc;
        f32x4 acc[4] = {{0.f,0.f,0.f,0.f},{0.f,0.f,0.f,0.f},{0.f,0.f,0.f,0.f},{0.f,0.f,0.f,0.f}};

        for (int kc = 0; kc < 4; ++kc) {
            __syncthreads();
            for (int p = tid; p < 4096; p += 512) {
                int row = p >> 6, pk = (p & 63) * 2;
                int k = kc * 128 + pk;
                float vx = 0.f, vy = 0.f;
                if (k < 400) {
                    float2 v = *(const float2*)(p2 + (size_t)(n0 + row) * 400 + k);
                    vx = v.x; vy = v.y;
                }
                _Float16 h0 = (_Float16)vx, h1 = (_Float16)vy;
                _Float16 l0 = (_Float16)(vx - (float)h0), l1 = (_Float16)(vy - (float)h1);
                hplu[row * 68 + (pk >> 1)]        = packhh(h0, h1);
                hplu[4352 + row * 68 + (pk >> 1)] = packhh(l0, l1);
            }
            __syncthreads();
            const int nslice = (kc < 3) ? 4 : 1;
            for (int s = 0; s < nslice; ++s) {
                const int kbase = kc * 128 + s * 32 + g * 8;
                float fa[8] = {0.f,0.f,0.f,0.f,0.f,0.f,0.f,0.f};
                if (outg < 120 && kbase + 7 < 400) {
                    float4 va = *(const float4*)(f1w + (size_t)outg * 400 + kbase);
                    float4 vb = *(const float4*)(f1w + (size_t)outg * 400 + kbase + 4);
                    fa[0]=va.x; fa[1]=va.y; fa[2]=va.z; fa[3]=va.w;
                    fa[4]=vb.x; fa[5]=vb.y; fa[6]=vb.z; fa[7]=vb.w;
                }
                half8 ah, al;
                #pragma unroll
                for (int j = 0; j < 8; ++j) {
                    _Float16 h = (_Float16)fa[j];
                    ah[j] = h;
                    al[j] = (_Float16)(fa[j] - (float)h);
                }
                #pragma unroll
                for (int nt = 0; nt < 4; ++nt) {
                    const int row = nt * 16 + cc;
                    uint4 hv = *(const uint4*)(hplu + row * 68 + s * 16 + g * 4);
                    uint4 lv = *(const uint4*)(hplu + 4352 + row * 68 + s * 16 + g * 4);
                    half8 bh8 = __builtin_bit_cast(half8, hv);
                    half8 bl8 = __builtin_bit_cast(half8, lv);
                    acc[nt] = __builtin_amdgcn_mfma_f32_16x16x32_f16(ah, bh8, acc[nt], 0, 0, 0);
                    acc[nt] = __builtin_amdgcn_mfma_f32_16x16x32_f16(ah, bl8, acc[nt], 0, 0, 0);
                    acc[nt] = __builtin_amdgcn_mfma_f32_16x16x32_f16(al, bh8, acc[nt], 0, 0, 0);
                }
            }
        }
        __syncthreads();
        float bo[4]; int ov[4];
        #pragma unroll
        for (int i2 = 0; i2 < 4; ++i2) {
            ov[i2] = wvv * 16 + g * 4 + i2;
            bo[i2] = (ov[i2] < 120) ? f1b[ov[i2]] : 0.f;
        }
        #pragma unroll
        for (int nt = 0; nt < 4; ++nt) {
            const int token = nt * 16 + cc;
            #pragma unroll
            for (int i2 = 0; i2 < 4; ++i2) {
                if (ov[i2] < 120)
                    sh1[token * 121 + ov[i2]] = fmaxf(acc[nt][i2] + bo[i2], 0.f);
            }
        }
    }

    float* sfw  = region;
    float* sC   = region + 10164;
    float* sh   = region + 16964;
    float* sgw  = region + 22404;
    float* shb2s= region + 23076;
    float* shb  = region + 23156;
    float* slog = region + 23168;
    float* swt2 = region + 23744;

    for (int i = tid; i < 2520; i += 512) {
        int o = i / 30, k4 = (i % 30) * 4;
        float4 v = *(const float4*)(f2w + (size_t)o * 120 + k4);
        float* d = sfw + o * 121 + k4;
        d[0] = v.x; d[1] = v.y; d[2] = v.z; d[3] = v.w;
    }
    for (int i = tid; i < 6720; i += 512) sC[(i / 84) * 85 + (i % 84)] = Cw[i];
    for (int i = tid; i < 672; i += 512) sgw[i] = gw[i];
    if (tid < 80) shb2s[tid] = hb2[tid];
    if (tid < 10) shb[tid] = headb[tid];
    if (tid < 84) sfb[tid] = f2b[tid];
    __syncthreads();

    for (int i = tid; i < 5376; i += 512) {
        const int t = i / 84, o = i % 84;
        const float* a = sh1 + t * 121;
        const float* wr = sfw + o * 121;
        float s = 0.f;
        #pragma unroll 8
        for (int k = 0; k < 120; ++k) s = fmaf(a[k], wr[k], s);
        sh[t * 85 + o] = fmaxf(s + sfb[o], 0.f);
    }
    __syncthreads();

    {
        const int t = tid / 8, e = tid % 8;
        const float* a = sh + t * 85;
        float s = 0.f;
        #pragma unroll 4
        for (int d = 0; d < 84; ++d) s = fmaf(a[d], sgw[d * 8 + e], s);
        slog[t * 9 + e] = s;
    }
    __syncthreads();

    if (tid < 64) {
        const float* l = slog + tid * 9;
        float m1 = l[0]; int i1 = 0;
        #pragma unroll
        for (int e = 1; e < 8; ++e) if (l[e] > m1) { m1 = l[e]; i1 = e; }
        float m2 = -1e30f; int i2 = 0;
        #pragma unroll
        for (int e = 0; e < 8; ++e) if (e != i1 && l[e] > m2) { m2 = l[e]; i2 = e; }
        const float r = expf(m2 - m1);
        const float inv = 1.f / (1.f + r);
        swt2[tid * 2] = inv; swt2[tid * 2 + 1] = r * inv;
        sei[tid * 2] = i1; sei[tid * 2 + 1] = i2;
    }
    __syncthreads();

    for (int i = tid; i < 640; i += 512) {
        const int t = i / 10, o = i % 10;
        const float* a = sh + t * 85;
        const float w0 = swt2[t * 2], w1 = swt2[t * 2 + 1];
        const int e0 = sei[t * 2], e1 = sei[t * 2 + 1];
        const float* c0 = sC + (e0 * 10 + o) * 85;
        const float* c1 = sC + (e1 * 10 + o) * 85;
        float s0 = 0.f, s1 = 0.f;
        #pragma unroll 4
        for (int d = 0; d < 84; ++d) {
            s0 = fmaf(a[d], c0[d], s0);
            s1 = fmaf(a[d], c1[d], s1);
        }
        out[(size_t)(n0 + t) * 10 + o] =
            shb[o] + w0 * (s0 + shb2s[e0 * 10 + o]) + w1 * (s1 + shb2s[e1 * 10 + o]);
    }
}

extern "C" void kernel_launch(void* const* d_in, const int* in_sizes, int n_in,
                              void* d_out, int out_size, void* d_ws, size_t ws_size,
                              hipStream_t stream) {
    const float* x   = (const float*)d_in[0];
    const float* c1w = (const float*)d_in[1];
    const float* c1b = (const float*)d_in[2];
    const float* c2w = (const float*)d_in[3];
    const float* c2b = (const float*)d_in[4];
    const float* f1w = (const float*)d_in[5];
    const float* f1b = (const float*)d_in[6];
    const float* f2w = (const float*)d_in[7];
    const float* f2b = (const float*)d_in[8];
    const float* gw  = (const float*)d_in[9];
    const float* ew  = (const float*)d_in[10];
    const float* eb  = (const float*)d_in[11];
    const float* hw  = (const float*)d_in[12];
    const float* hb  = (const float*)d_in[13];
    float* out = (float*)d_out;

    const int N = in_sizes[0] / 3072;   // 16384

    float* ws = (float*)d_ws;
    uint*  p1  = (uint*)ws;                    // N*1176 uints (compact packed hi/lo)
    float* p2  = ws + (size_t)N * 1176;        // N*400
    float* C   = p2 + (size_t)N * 400;         // 6720
    float* hb2 = C + 6720;                     // 80

    k_conv1<<<N / 2, 512, 0, stream>>>(x, c1w, c1b, p1);
    k_conv2<<<N / 4, 256, 0, stream>>>(p1, c2w, c2b, p2);
    k_compose<<<8, 256, 0, stream>>>(ew, eb, hw, C, hb2);
    k_fc1tail<<<N / 64, 512, 0, stream>>>(p2, f1w, f1b, f2w, f2b, gw, C, hb2, hb, out);
}

// Round 21
// 261.725 us; speedup vs baseline: 1.0889x; 1.0889x over previous
//
#include <hip/hip_runtime.h>
#include <math.h>

typedef _Float16 half8 __attribute__((ext_vector_type(8)));
typedef float f32x4 __attribute__((ext_vector_type(4)));

__device__ inline uint splitpack(float v) {
    _Float16 h = (_Float16)v;
    float r = v - (float)h;
    _Float16 l = (_Float16)r;
    return (uint)__builtin_bit_cast(unsigned short, h) |
           ((uint)__builtin_bit_cast(unsigned short, l) << 16);
}
__device__ inline _Float16 lo16h(uint u) { return __builtin_bit_cast(_Float16, (unsigned short)(u & 0xffffu)); }
__device__ inline _Float16 hi16h(uint u) { return __builtin_bit_cast(_Float16, (unsigned short)(u >> 16)); }
__device__ inline uint packhh(_Float16 a, _Float16 b) {
    return (uint)__builtin_bit_cast(unsigned short, a) |
           ((uint)__builtin_bit_cast(unsigned short, b) << 16);
}
__device__ inline float dpp_max8(float v) {
    int x = __builtin_amdgcn_mov_dpp(__builtin_bit_cast(int, v), 0x128, 0xf, 0xf, true);
    return fmaxf(v, __builtin_bit_cast(float, x));
}

// ---------------- conv1: x -> p1 packed, COMPACT layout [N][6][196] (dense-line writes) ----------------
__global__ __launch_bounds__(256) void k_conv1(const float* __restrict__ x,
                                               const float* __restrict__ w,
                                               const float* __restrict__ b,
                                               uint* __restrict__ p1) {
    __shared__ uint simg[6720];
    const int tid  = threadIdx.x;
    const int lane = tid & 63;
    const int wv   = tid >> 6;
    const int n0   = blockIdx.x * 2;

    const int colb = lane & 15;
    const int c  = colb & 7, dx = colb >> 3;
    const int g  = lane >> 4;
    const int qr = g;

    half8 bh[3], bl[3];
    #pragma unroll
    for (int ks = 0; ks < 3; ++ks)
        #pragma unroll
        for (int jj = 0; jj < 8; ++jj) {
            int pi = jj >> 1, e = jj & 1;
            int rho = g * 4 + pi;
            float val = 0.f;
            if (rho < 15 && c < 6) {
                int ci = rho / 5, ky = rho % 5;
                int kx = ks * 2 + e - dx;
                if (kx >= 0 && kx < 5) val = w[c * 75 + ci * 25 + ky * 5 + kx];
            }
            _Float16 hh = (_Float16)val;
            bh[ks][jj] = hh;
            bl[ks][jj] = (_Float16)(val - (float)hh);
        }
    const float bias = (c < 6) ? b[c] : 0.f;

    for (int i = tid; i < 1536; i += 256) {
        int im = i / 768;
        int rem = i - im * 768;
        int plane = rem >> 8, rr = (rem & 255) >> 3, f = rem & 7;
        float4 v = *(const float4*)(x + ((size_t)(n0 + im) * 3 + plane) * 1024 + rr * 32 + f * 4);
        _Float16 h0 = (_Float16)v.x, h1 = (_Float16)v.y, h2 = (_Float16)v.z, h3 = (_Float16)v.w;
        _Float16 l0 = (_Float16)(v.x - (float)h0), l1 = (_Float16)(v.y - (float)h1);
        _Float16 l2 = (_Float16)(v.z - (float)h2), l3 = (_Float16)(v.w - (float)h3);
        int base = im * 3360 + plane * 1120 + rr * 35 + f * 2;
        simg[base]      = packhh(h0, h1);
        simg[base + 1]  = packhh(h2, h3);
        simg[base + 16] = packhh(l0, l1);
        simg[base + 17] = packhh(l2, l3);
    }
    __syncthreads();

    int poff[4];
    #pragma unroll
    for (int pi = 0; pi < 4; ++pi) {
        int rho = g * 4 + pi;
        if (rho > 14) rho = 14;
        poff[pi] = (rho / 5) * 1120 + (rho % 5) * 35;
    }

    for (int t0 = wv; t0 < 50; t0 += 8) {
        const int t1 = (t0 + 4 < 50) ? (t0 + 4) : t0;
        const int im0 = (t0 >= 25) ? 1 : 0, tl0 = t0 - im0 * 25;
        const int im1 = (t1 >= 25) ? 1 : 0, tl1 = t1 - im1 * 25;
        int r0c = tl0 * 16 + colb; if (r0c > 391) r0c = 391;
        int r1c = tl1 * 16 + colb; if (r1c > 391) r1c = 391;
        int qx0 = (r0c * 586) >> 14, yy0 = r0c - qx0 * 28;
        int qx1 = (r1c * 586) >> 14, yy1 = r1c - qx1 * 28;
        const uint* base0 = simg + im0 * 3360 + yy0 * 35 + qx0;
        const uint* base1 = simg + im1 * 3360 + yy1 * 35 + qx1;

        f32x4 A0[2] = {{0.f,0.f,0.f,0.f},{0.f,0.f,0.f,0.f}};
        f32x4 A1[2] = {{0.f,0.f,0.f,0.f},{0.f,0.f,0.f,0.f}};
        int c0 = 0, c1 = 0;
        #pragma unroll
        for (int ks = 0; ks < 3; ++ks) {
            uint h0[4], l0[4], h1[4], l1[4];
            #pragma unroll
            for (int pi = 0; pi < 4; ++pi) {
                const uint* a0p = base0 + poff[pi];
                const uint* a1p = base1 + poff[pi];
                h0[pi] = a0p[ks];  l0[pi] = a0p[16 + ks];
                h1[pi] = a1p[ks];  l1[pi] = a1p[16 + ks];
            }
            uint4 hv0; hv0.x = h0[0]; hv0.y = h0[1]; hv0.z = h0[2]; hv0.w = h0[3];
            uint4 lv0; lv0.x = l0[0]; lv0.y = l0[1]; lv0.z = l0[2]; lv0.w = l0[3];
            uint4 hv1; hv1.x = h1[0]; hv1.y = h1[1]; hv1.z = h1[2]; hv1.w = h1[3];
            uint4 lv1; lv1.x = l1[0]; lv1.y = l1[1]; lv1.z = l1[2]; lv1.w = l1[3];
            half8 ah0 = __builtin_bit_cast(half8, hv0);
            half8 al0 = __builtin_bit_cast(half8, lv0);
            half8 ah1 = __builtin_bit_cast(half8, hv1);
            half8 al1 = __builtin_bit_cast(half8, lv1);
            A0[c0 & 1] = __builtin_amdgcn_mfma_f32_16x16x32_f16(ah0, bh[ks], A0[c0 & 1], 0, 0, 0); ++c0;
            A1[c1 & 1] = __builtin_amdgcn_mfma_f32_16x16x32_f16(ah1, bh[ks], A1[c1 & 1], 0, 0, 0); ++c1;
            A0[c0 & 1] = __builtin_amdgcn_mfma_f32_16x16x32_f16(ah0, bl[ks], A0[c0 & 1], 0, 0, 0); ++c0;
            A1[c1 & 1] = __builtin_amdgcn_mfma_f32_16x16x32_f16(ah1, bl[ks], A1[c1 & 1], 0, 0, 0); ++c1;
            A0[c0 & 1] = __builtin_amdgcn_mfma_f32_16x16x32_f16(al0, bh[ks], A0[c0 & 1], 0, 0, 0); ++c0;
            A1[c1 & 1] = __builtin_amdgcn_mfma_f32_16x16x32_f16(al1, bh[ks], A1[c1 & 1], 0, 0, 0); ++c1;
        }
        {
            f32x4 acc;
            #pragma unroll
            for (int i = 0; i < 4; ++i) acc[i] = A0[0][i] + A0[1][i];
            float p01 = dpp_max8(fmaxf(acc[0], acc[1]));
            float p23 = dpp_max8(fmaxf(acc[2], acc[3]));
            if (dx == 0 && c < 6) {
                uint* outb = p1 + (size_t)(n0 + im0) * 1176 + c * 196;
                int r0 = tl0 * 16 + qr * 4;
                if (r0 + 1 < 392) {
                    int qxa = (r0 * 586) >> 14, ya = r0 - qxa * 28;
                    outb[(ya >> 1) * 14 + qxa] = splitpack(fmaxf(p01 + bias, 0.f));
                }
                int r2 = r0 + 2;
                if (r2 + 1 < 392) {
                    int qxb = (r2 * 586) >> 14, yb = r2 - qxb * 28;
                    outb[(yb >> 1) * 14 + qxb] = splitpack(fmaxf(p23 + bias, 0.f));
                }
            }
        }
        if (t1 != t0) {
            f32x4 acc;
            #pragma unroll
            for (int i = 0; i < 4; ++i) acc[i] = A1[0][i] + A1[1][i];
            float p01 = dpp_max8(fmaxf(acc[0], acc[1]));
            float p23 = dpp_max8(fmaxf(acc[2], acc[3]));
            if (dx == 0 && c < 6) {
                uint* outb = p1 + (size_t)(n0 + im1) * 1176 + c * 196;
                int r0 = tl1 * 16 + qr * 4;
                if (r0 + 1 < 392) {
                    int qxa = (r0 * 586) >> 14, ya = r0 - qxa * 28;
                    outb[(ya >> 1) * 14 + qxa] = splitpack(fmaxf(p01 + bias, 0.f));
                }
                int r2 = r0 + 2;
                if (r2 + 1 < 392) {
                    int qxb = (r2 * 586) >> 14, yb = r2 - qxb * 28;
                    outb[(yb >> 1) * 14 + qxb] = splitpack(fmaxf(p23 + bias, 0.f));
                }
            }
        }
    }
}

// ---------------- conv2: compact p1 -> p2 fp32; linear staging, stride-14 LDS rows ----------------
// kx=5 pad slots (B=0) read "col 14" = next row's col 0 (real finite data x 0) — deterministic.
// Final one-past-end read (last img, last row) lands in the zeroed 8-dword tail.
__global__ __launch_bounds__(256) void k_conv2(const uint* __restrict__ p1,
                                               const float* __restrict__ w,
                                               const float* __restrict__ b,
                                               float* __restrict__ p2) {
    __shared__ __align__(16) uint simg[4 * 1176 + 8];
    const int tid  = threadIdx.x;
    const int lane = tid & 63;
    const int wv   = tid >> 6;
    const int n0   = blockIdx.x * 4;
    const int g  = lane >> 4;
    const int cc = lane & 15;
    const int qr = g;

    {   // 4 imgs * 1176 uints = 1176 uint4, straight copy
        const uint4* pg = (const uint4*)(p1 + (size_t)n0 * 1176);
        uint4* sg = (uint4*)simg;
        for (int i = tid; i < 1176; i += 256) sg[i] = pg[i];
        if (tid < 8) simg[4704 + tid] = 0u;   // zero tail for one-past-end pad reads
    }

    half8 bh[6], bl[6];
    #pragma unroll
    for (int ks = 0; ks < 6; ++ks)
        #pragma unroll
        for (int jj = 0; jj < 8; ++jj) {
            int pi = jj >> 1, e = jj & 1;
            int rho = (ks / 3) * 16 + g * 4 + pi;
            int kx = (ks % 3) * 2 + e;
            float val = 0.f;
            if (rho < 30 && kx < 5) {
                int ci = rho / 5, ky = rho % 5;
                val = w[cc * 150 + ci * 25 + ky * 5 + kx];
            }
            _Float16 hh = (_Float16)val;
            bh[ks][jj] = hh;
            bl[ks][jj] = (_Float16)(val - (float)hh);
        }
    const float bias = b[cc];
    __syncthreads();

    int poff2[8];
    #pragma unroll
    for (int sp = 0; sp < 8; ++sp) {
        int sel = sp >> 2, pi = sp & 3;
        int rho = sel * 16 + g * 4 + pi;
        if (rho > 29) rho = 29;
        poff2[sp] = (rho / 5) * 196 + (rho % 5) * 14;
    }

    const uint* img = simg + wv * 1176;
    const int qw  = (lane & 15) >> 2;
    const int dy  = (lane >> 1) & 1, dxx = lane & 1;
    float* outb = p2 + (size_t)(n0 + wv) * 400 + cc * 25;

    for (int t = 0; t < 7; ++t) {
        int qa = t * 4 + qw; if (qa > 24) qa = 24;
        int qy = qa / 5, qx = qa % 5;
        int base = (2 * qy + dy) * 14 + (2 * qx + dxx);
        f32x4 acc2[2] = {{0.f,0.f,0.f,0.f},{0.f,0.f,0.f,0.f}};
        int pp = 0;
        #pragma unroll
        for (int sel = 0; sel < 2; ++sel) {
            uint P[4][6];
            #pragma unroll
            for (int pi = 0; pi < 4; ++pi) {
                const uint* ap = img + base + poff2[sel * 4 + pi];
                #pragma unroll
                for (int k = 0; k < 6; ++k) P[pi][k] = ap[k];  // 3x ds_read2_b32
            }
            #pragma unroll
            for (int ksr = 0; ksr < 3; ++ksr) {
                const int ks = sel * 3 + ksr;
                uint hu[4], lu[4];
                #pragma unroll
                for (int pi = 0; pi < 4; ++pi) {
                    uint d0 = P[pi][ksr * 2], d1 = P[pi][ksr * 2 + 1];
                    hu[pi] = __builtin_amdgcn_perm(d1, d0, 0x05040100u);
                    lu[pi] = __builtin_amdgcn_perm(d1, d0, 0x07060302u);
                }
                uint4 hv; hv.x = hu[0]; hv.y = hu[1]; hv.z = hu[2]; hv.w = hu[3];
                uint4 lv; lv.x = lu[0]; lv.y = lu[1]; lv.z = lu[2]; lv.w = lu[3];
                half8 ah = __builtin_bit_cast(half8, hv);
                half8 al = __builtin_bit_cast(half8, lv);
                acc2[pp & 1] = __builtin_amdgcn_mfma_f32_16x16x32_f16(ah, bh[ks], acc2[pp & 1], 0, 0, 0); ++pp;
                acc2[pp & 1] = __builtin_amdgcn_mfma_f32_16x16x32_f16(ah, bl[ks], acc2[pp & 1], 0, 0, 0); ++pp;
                acc2[pp & 1] = __builtin_amdgcn_mfma_f32_16x16x32_f16(al, bh[ks], acc2[pp & 1], 0, 0, 0); ++pp;
            }
        }
        int qc = t * 4 + qr;
        if (qc < 25) {
            float m = fmaxf(fmaxf(acc2[0][0] + acc2[1][0], acc2[0][1] + acc2[1][1]),
                            fmaxf(acc2[0][2] + acc2[1][2], acc2[0][3] + acc2[1][3]));
            outb[qc] = fmaxf(m + bias, 0.f);
        }
    }
}

// ---------------- compose: C[e][o][d] = sum_j head_w[o][j]*expert_w[e][j][d] ----------------
__global__ __launch_bounds__(256) void k_compose(const float* __restrict__ ew,
                                                 const float* __restrict__ eb,
                                                 const float* __restrict__ hw,
                                                 float* __restrict__ C,
                                                 float* __restrict__ hb2) {
    __shared__ float shw[840];
    __shared__ float seb[672];
    const int e = blockIdx.x, tid = threadIdx.x;
    for (int i = tid; i < 840; i += 256) shw[i] = hw[i];
    for (int i = tid; i < 672; i += 256) seb[i] = eb[i];
    __syncthreads();
    for (int i = tid; i < 840; i += 256) {
        int o = i / 84, d = i % 84;
        float s = 0.f;
        for (int j = 0; j < 84; ++j)
            s = fmaf(shw[o * 84 + j], ew[((size_t)e * 84 + j) * 84 + d], s);
        C[e * 840 + i] = s;
    }
    if (tid < 10) {
        float s = 0.f;
        for (int j = 0; j < 84; ++j) s = fmaf(shw[tid * 84 + j], seb[e * 84 + j], s);
        hb2[e * 10 + tid] = s;
    }
}

// ---------------- fused fc1(MFMA)+fc2+gate+MoE+head ----------------
__global__ __launch_bounds__(512) void k_fc1tail(const float* __restrict__ p2,
                                                 const float* __restrict__ f1w,
                                                 const float* __restrict__ f1b,
                                                 const float* __restrict__ f2w,
                                                 const float* __restrict__ f2b,
                                                 const float* __restrict__ gw,
                                                 const float* __restrict__ Cw,
                                                 const float* __restrict__ hb2,
                                                 const float* __restrict__ headb,
                                                 float* __restrict__ out) {
    __shared__ __align__(16) float region[23872];
    __shared__ float sh1[7744];          // h1: [64][121]
    __shared__ float sfb[84];
    __shared__ int   sei[128];
    const int tid = threadIdx.x;
    const int n0 = blockIdx.x * 64;

    // ---------- phase 1: fc1 via MFMA ----------
    {
        uint* hplu = (uint*)region;
        const int lane = tid & 63;
        const int wvv  = tid >> 6;
        const int cc = lane & 15, g = lane >> 4;
        const int outg = wvv * 16 + cc;
        f32x4 acc[4] = {{0.f,0.f,0.f,0.f},{0.f,0.f,0.f,0.f},{0.f,0.f,0.f,0.f},{0.f,0.f,0.f,0.f}};

        for (int kc = 0; kc < 4; ++kc) {
            __syncthreads();
            for (int p = tid; p < 4096; p += 512) {
                int row = p >> 6, pk = (p & 63) * 2;
                int k = kc * 128 + pk;
                float vx = 0.f, vy = 0.f;
                if (k < 400) {
                    float2 v = *(const float2*)(p2 + (size_t)(n0 + row) * 400 + k);
                    vx = v.x; vy = v.y;
                }
                _Float16 h0 = (_Float16)vx, h1 = (_Float16)vy;
                _Float16 l0 = (_Float16)(vx - (float)h0), l1 = (_Float16)(vy - (float)h1);
                hplu[row * 68 + (pk >> 1)]        = packhh(h0, h1);
                hplu[4352 + row * 68 + (pk >> 1)] = packhh(l0, l1);
            }
            __syncthreads();
            const int nslice = (kc < 3) ? 4 : 1;
            for (int s = 0; s < nslice; ++s) {
                const int kbase = kc * 128 + s * 32 + g * 8;
                float fa[8] = {0.f,0.f,0.f,0.f,0.f,0.f,0.f,0.f};
                if (outg < 120 && kbase + 7 < 400) {
                    float4 va = *(const float4*)(f1w + (size_t)outg * 400 + kbase);
                    float4 vb = *(const float4*)(f1w + (size_t)outg * 400 + kbase + 4);
                    fa[0]=va.x; fa[1]=va.y; fa[2]=va.z; fa[3]=va.w;
                    fa[4]=vb.x; fa[5]=vb.y; fa[6]=vb.z; fa[7]=vb.w;
                }
                half8 ah, al;
                #pragma unroll
                for (int j = 0; j < 8; ++j) {
                    _Float16 h = (_Float16)fa[j];
                    ah[j] = h;
                    al[j] = (_Float16)(fa[j] - (float)h);
                }
                #pragma unroll
                for (int nt = 0; nt < 4; ++nt) {
                    const int row = nt * 16 + cc;
                    uint4 hv = *(const uint4*)(hplu + row * 68 + s * 16 + g * 4);
                    uint4 lv = *(const uint4*)(hplu + 4352 + row * 68 + s * 16 + g * 4);
                    half8 bh8 = __builtin_bit_cast(half8, hv);
                    half8 bl8 = __builtin_bit_cast(half8, lv);
                    acc[nt] = __builtin_amdgcn_mfma_f32_16x16x32_f16(ah, bh8, acc[nt], 0, 0, 0);
                    acc[nt] = __builtin_amdgcn_mfma_f32_16x16x32_f16(ah, bl8, acc[nt], 0, 0, 0);
                    acc[nt] = __builtin_amdgcn_mfma_f32_16x16x32_f16(al, bh8, acc[nt], 0, 0, 0);
                }
            }
        }
        __syncthreads();
        float bo[4]; int ov[4];
        #pragma unroll
        for (int i2 = 0; i2 < 4; ++i2) {
            ov[i2] = wvv * 16 + g * 4 + i2;
            bo[i2] = (ov[i2] < 120) ? f1b[ov[i2]] : 0.f;
        }
        #pragma unroll
        for (int nt = 0; nt < 4; ++nt) {
            const int token = nt * 16 + cc;
            #pragma unroll
            for (int i2 = 0; i2 < 4; ++i2) {
                if (ov[i2] < 120)
                    sh1[token * 121 + ov[i2]] = fmaxf(acc[nt][i2] + bo[i2], 0.f);
            }
        }
    }

    // ---------- phase 2: fc2 + gate + top2 + MoE + head ----------
    float* sfw  = region;
    float* sC   = region + 10164;
    float* sh   = region + 16964;
    float* sgw  = region + 22404;
    float* shb2s= region + 23076;
    float* shb  = region + 23156;
    float* slog = region + 23168;
    float* swt2 = region + 23744;

    for (int i = tid; i < 2520; i += 512) {
        int o = i / 30, k4 = (i % 30) * 4;
        float4 v = *(const float4*)(f2w + (size_t)o * 120 + k4);
        float* d = sfw + o * 121 + k4;
        d[0] = v.x; d[1] = v.y; d[2] = v.z; d[3] = v.w;
    }
    for (int i = tid; i < 6720; i += 512) sC[(i / 84) * 85 + (i % 84)] = Cw[i];
    for (int i = tid; i < 672; i += 512) sgw[i] = gw[i];
    if (tid < 80) shb2s[tid] = hb2[tid];
    if (tid < 10) shb[tid] = headb[tid];
    if (tid < 84) sfb[tid] = f2b[tid];
    __syncthreads();

    for (int i = tid; i < 5376; i += 512) {
        const int t = i / 84, o = i % 84;
        const float* a = sh1 + t * 121;
        const float* wr = sfw + o * 121;
        float s = 0.f;
        #pragma unroll 8
        for (int k = 0; k < 120; ++k) s = fmaf(a[k], wr[k], s);
        sh[t * 85 + o] = fmaxf(s + sfb[o], 0.f);
    }
    __syncthreads();

    {
        const int t = tid / 8, e = tid % 8;
        const float* a = sh + t * 85;
        float s = 0.f;
        #pragma unroll 4
        for (int d = 0; d < 84; ++d) s = fmaf(a[d], sgw[d * 8 + e], s);
        slog[t * 9 + e] = s;
    }
    __syncthreads();

    if (tid < 64) {
        const float* l = slog + tid * 9;
        float m1 = l[0]; int i1 = 0;
        #pragma unroll
        for (int e = 1; e < 8; ++e) if (l[e] > m1) { m1 = l[e]; i1 = e; }
        float m2 = -1e30f; int i2 = 0;
        #pragma unroll
        for (int e = 0; e < 8; ++e) if (e != i1 && l[e] > m2) { m2 = l[e]; i2 = e; }
        const float r = expf(m2 - m1);
        const float inv = 1.f / (1.f + r);
        swt2[tid * 2] = inv; swt2[tid * 2 + 1] = r * inv;
        sei[tid * 2] = i1; sei[tid * 2 + 1] = i2;
    }
    __syncthreads();

    for (int i = tid; i < 640; i += 512) {
        const int t = i / 10, o = i % 10;
        const float* a = sh + t * 85;
        const float w0 = swt2[t * 2], w1 = swt2[t * 2 + 1];
        const int e0 = sei[t * 2], e1 = sei[t * 2 + 1];
        const float* c0 = sC + (e0 * 10 + o) * 85;
        const float* c1 = sC + (e1 * 10 + o) * 85;
        float s0 = 0.f, s1 = 0.f;
        #pragma unroll 4
        for (int d = 0; d < 84; ++d) {
            s0 = fmaf(a[d], c0[d], s0);
            s1 = fmaf(a[d], c1[d], s1);
        }
        out[(size_t)(n0 + t) * 10 + o] =
            shb[o] + w0 * (s0 + shb2s[e0 * 10 + o]) + w1 * (s1 + shb2s[e1 * 10 + o]);
    }
}

extern "C" void kernel_launch(void* const* d_in, const int* in_sizes, int n_in,
                              void* d_out, int out_size, void* d_ws, size_t ws_size,
                              hipStream_t stream) {
    const float* x   = (const float*)d_in[0];
    const float* c1w = (const float*)d_in[1];
    const float* c1b = (const float*)d_in[2];
    const float* c2w = (const float*)d_in[3];
    const float* c2b = (const float*)d_in[4];
    const float* f1w = (const float*)d_in[5];
    const float* f1b = (const float*)d_in[6];
    const float* f2w = (const float*)d_in[7];
    const float* f2b = (const float*)d_in[8];
    const float* gw  = (const float*)d_in[9];
    const float* ew  = (const float*)d_in[10];
    const float* eb  = (const float*)d_in[11];
    const float* hw  = (const float*)d_in[12];
    const float* hb  = (const float*)d_in[13];
    float* out = (float*)d_out;

    const int N = in_sizes[0] / 3072;   // 16384

    float* ws = (float*)d_ws;
    uint*  p1  = (uint*)ws;                    // N*1176 uints (compact packed hi/lo)
    float* p2  = ws + (size_t)N * 1176;        // N*400
    float* C   = p2 + (size_t)N * 400;         // 6720
    float* hb2 = C + 6720;                     // 80

    k_conv1<<<N / 2, 256, 0, stream>>>(x, c1w, c1b, p1);
    k_conv2<<<N / 4, 256, 0, stream>>>(p1, c2w, c2b, p2);
    k_compose<<<8, 256, 0, stream>>>(ew, eb, hw, C, hb2);
    k_fc1tail<<<N / 64, 512, 0, stream>>>(p2, f1w, f1b, f2w, f2b, gw, C, hb2, hb, out);
}